// Round 11
// baseline (1090.324 us; speedup 1.0000x reference)
//
#include <hip/hip_runtime.h>
#include <hip/hip_cooperative_groups.h>
#include <math.h>

namespace cg = cooperative_groups;

#define NN 50000
#define NE 800000
#define IN_CH 64
#define HEADS 8
#define OC 16
#define HID 128
#define NG 500
#define GB2 ((NN + 63) / 64)        // 782 GEMM tiles (64 nodes)
#define SB 3125                     // fallback scatter blocks (1 edge/thread)
#define PB 96                       // fallback prep blocks
#define NGRP 8                      // XCD-private CSR groups
#define SLOTG 8                     // slots per node per group
#define OVS 64                      // overflow slots per node
#define XP 72                       // xb LDS pitch (bf16)
#define WP 72                       // wt LDS pitch (bf16)
#define AGB 2048                    // fallback k_agg grid

typedef float v2f __attribute__((ext_vector_type(2)));
typedef _Float16 h2 __attribute__((ext_vector_type(2)));
typedef __attribute__((ext_vector_type(8))) short frag8;
typedef __attribute__((ext_vector_type(4))) float f32x4;

__device__ __forceinline__ unsigned bf16rn(float f) {
    unsigned u = __float_as_uint(f);
    return (u + 0x7fffu + ((u >> 16) & 1u)) >> 16;
}

// Sum across a 4-lane quad (head = 16 ch = 4 lanes at 4 ch/lane).
__device__ __forceinline__ float dpp4_sum(float x) {
    int t;
    t = __builtin_amdgcn_update_dpp(0, __float_as_int(x), 0xB1, 0xF, 0xF, true);
    x += __int_as_float(t);
    t = __builtin_amdgcn_update_dpp(0, __float_as_int(x), 0x4E, 0xF, 0xF, true);
    x += __int_as_float(t);
    return x;
}

#if __has_builtin(__builtin_amdgcn_fdot2)
#define FDOT2A(a, b, c) __builtin_amdgcn_fdot2((a), (b), (c), false)
#else
__device__ __forceinline__ float FDOT2A(h2 a, h2 b, float c) {
    v2f af = __builtin_convertvector(a, v2f);
    v2f bf = __builtin_convertvector(b, v2f);
    return af.x * bf.x + af.y * bf.y + c;
}
#endif

#if __has_builtin(__builtin_amdgcn_exp2f)
#define EXP2(x) __builtin_amdgcn_exp2f(x)
#else
#define EXP2(x) exp2f(x)
#endif

// grid.sync() is NOT a cross-XCD coherence point; wrap with agent-scope
// release/acquire (buffer_wbl2/buffer_inv) to reproduce a kernel boundary.
__device__ __forceinline__ void xsync(cg::grid_group& g) {
    __builtin_amdgcn_fence(__ATOMIC_RELEASE, "agent");
    g.sync();
    __builtin_amdgcn_fence(__ATOMIC_ACQUIRE, "agent");
}

// per-edge math at 4 ch/lane; one wave-inst serves 2 edges (2 nodes/wave).
__device__ __forceinline__ void edge4(uint2 vv, h2 xr01, h2 xr23, h2 a01, h2 a23,
                                      bool pred, float& den,
                                      float& c0, float& c1, float& c2, float& c3) {
    const h2 x01 = __builtin_bit_cast(h2, vv.x);
    const h2 x23 = __builtin_bit_cast(h2, vv.y);
    const h2 t01 = x01 + xr01;
    const h2 t23 = x23 + xr23;
    const h2 e01 = __builtin_elementwise_max(t01, t01 * (_Float16)0.2f);
    const h2 e23 = __builtin_elementwise_max(t23, t23 * (_Float16)0.2f);
    const float q = dpp4_sum(FDOT2A(e23, a23, FDOT2A(e01, a01, 0.f)));
    const float w = EXP2(q);
    if (pred) {
        den += w;
        const v2f f01 = __builtin_convertvector(x01, v2f);
        const v2f f23 = __builtin_convertvector(x23, v2f);
        c0 += w * f01.x; c1 += w * f01.y; c2 += w * f23.x; c3 += w * f23.y;
    }
}

// =============================================================================
// R31 mega: grid-size-agnostic phases; launched with occupancy-derived grid
// and an ERROR-CHECKED cooperative launch (R29/R30's bit-identical failure
// implies the kernel never ran — unchecked launch, output stayed zeros).
// =============================================================================
__global__ __launch_bounds__(256, 8) void k_mega(
    const float* __restrict__ x, const int* __restrict__ ei,
    const float* __restrict__ Wl, const float* __restrict__ bl,
    const float* __restrict__ Wr, const float* __restrict__ br,
    const float* __restrict__ Wres, const float* __restrict__ att,
    const float* __restrict__ bias,
    const float* __restrict__ Wlin, const float* __restrict__ blin,
    const float* __restrict__ W1, const float* __restrict__ b1,
    const float* __restrict__ W2, const float* __restrict__ b2,
    const float* __restrict__ W3, const float* __restrict__ b3,
    const int* __restrict__ batch, float* __restrict__ out,
    unsigned short* __restrict__ xlh, unsigned short* __restrict__ xrh,
    unsigned short* __restrict__ xresh, float* __restrict__ hfeat,
    int* __restrict__ cnt, unsigned short* __restrict__ col_src,
    unsigned short* __restrict__ ov, unsigned short* __restrict__ csr,
    int* __restrict__ degv, unsigned short* __restrict__ Wt)
{
    cg::grid_group grid = cg::this_grid();
    const int tid = threadIdx.x;
    const int bid = blockIdx.x;
    const int gtid = bid * 256 + tid;
    const int nthr = (int)gridDim.x << 8;      // blocks * 256
    const int nwav = nthr >> 6;
    const int lane = tid & 63;
    const int wv = tid >> 6;

    __shared__ union SMem {
        struct { short xb[64 * XP]; short wt[64 * WP]; } w;          // 17408 B
        struct {
            float sWlin[HID * 16]; float sW1[256]; float sW2[512]; float sW3[160];
            float sblin[16]; float sb1[16]; float sb2[32]; float sb3[5];
            float red[4][16]; float sg[16]; float sv1[16]; float sv2[32];
        } t;
    } sm;

    // ---- P0: zero cnt + pre-transpose W -> bf16 Wt (grid-stride) ----------
    for (int i = gtid; i < (NGRP + 1) * NN + 3 * 64 * HID; i += nthr) {
        if (i < (NGRP + 1) * NN) {
            cnt[i] = 0;
        } else {
            const int j = i - (NGRP + 1) * NN;
            const int m = j >> 13, r = j & 8191, k = r >> 7, c = r & 127;
            const float* W = (m == 0) ? Wl : (m == 1) ? Wr : Wres;
            Wt[(size_t)m * 8192 + c * 64 + k] = (unsigned short)bf16rn(W[k * HID + c]);
        }
    }
    xsync(grid);

    // ---- P1: scatter (XCD-private groups via real XCC_ID) -----------------
    for (int e = gtid; e < NE; e += nthr) {
        const int s = ei[e];
        const int d = ei[NE + e];
        if ((unsigned)d < NN) {
            int xcc;
            asm volatile("s_getreg_b32 %0, hwreg(HW_REG_XCC_ID)" : "=s"(xcc));
            const int g = xcc & (NGRP - 1);
            const int pos = __hip_atomic_fetch_add(&cnt[(size_t)g * NN + d], 1,
                                                   __ATOMIC_RELAXED,
                                                   __HIP_MEMORY_SCOPE_WORKGROUP);
            if (pos < SLOTG) {
                col_src[((size_t)g * NN + d) * SLOTG + pos] = (unsigned short)s;
            } else {
                const int po = atomicAdd(&cnt[(size_t)NGRP * NN + d], 1);
                if (po < OVS) ov[(size_t)d * OVS + po] = (unsigned short)s;
            }
        }
    }
    xsync(grid);

    // ---- P2: compact (all waves) + GEMM (blocks < GB2) --------------------
    {
        const int grp = lane >> 3;
        const int gsl = lane & 7;
        for (int n = gtid >> 6; n < NN; n += nwav) {
            int cg2 = cnt[(size_t)grp * NN + n];
            cg2 = min(max(cg2, 0), SLOTG);
            int cov = cnt[(size_t)NGRP * NN + n];
            cov = min(max(cov, 0), OVS);
            const bool valid = gsl < cg2;
            int slot = 0;
            if (valid) slot = (int)col_src[((size_t)grp * NN + n) * SLOTG + gsl];
            const unsigned long long mv = __ballot(valid);
            const int cn = __popcll(mv);
            const int pv = __popcll(mv & ((1ull << lane) - 1ull));
            const int dst = valid ? pv : (cn + (lane - pv));
            const int rec = __builtin_amdgcn_ds_permute(dst << 2, slot);
            if (lane < cn) csr[(size_t)n * 64 + lane] = (unsigned short)rec;
            const int take = min(cov, 64 - cn);
            if (lane < take) csr[(size_t)n * 64 + cn + lane] = ov[(size_t)n * OVS + lane];
            if (lane == 0) degv[n] = cn + take;
        }
    }
    if (bid < GB2) {
        const int n0 = bid * 64;
#pragma unroll
        for (int i = 0; i < 4; ++i) {
            const int idx = i * 256 + tid;
            const int r = idx >> 4, j4 = idx & 15;
            float4 v = make_float4(0.f, 0.f, 0.f, 0.f);
            if (n0 + r < NN) v = *(const float4*)(x + (size_t)(n0 + r) * IN_CH + j4 * 4);
            uint2 pk;
            pk.x = bf16rn(v.x) | (bf16rn(v.y) << 16);
            pk.y = bf16rn(v.z) | (bf16rn(v.w) << 16);
            *(uint2*)(sm.w.xb + r * XP + j4 * 4) = pk;
        }
        const int quad = lane >> 4;
        const int mr = lane & 15;
        const int m0 = wv * 16;
        __syncthreads();
        const frag8 a0 = *(const frag8*)(sm.w.xb + (m0 + mr) * XP + quad * 8);
        const frag8 a1 = *(const frag8*)(sm.w.xb + (m0 + mr) * XP + 32 + quad * 8);

        for (int mtx = 0; mtx < 3; ++mtx) {
            const unsigned short* __restrict__ Wtm = Wt + (size_t)mtx * 8192;
            unsigned short* __restrict__ outp = (mtx == 0) ? xlh : (mtx == 1) ? xrh : xresh;
            for (int ch = 0; ch < 2; ++ch) {
                __syncthreads();
#pragma unroll
                for (int i = 0; i < 2; ++i) {
                    const int idx = i * 256 + tid;
                    const int cl = idx >> 3, k0 = (idx & 7) * 8;
                    *(uint4*)(sm.w.wt + cl * WP + k0) =
                        *(const uint4*)(Wtm + (size_t)(ch * 64 + cl) * 64 + k0);
                }
                __syncthreads();
#pragma unroll
                for (int nt = 0; nt < 4; ++nt) {
                    const int cl = nt * 16 + mr;
                    const int c = ch * 64 + cl;
                    const frag8 b0 = *(const frag8*)(sm.w.wt + cl * WP + quad * 8);
                    const frag8 b1 = *(const frag8*)(sm.w.wt + cl * WP + 32 + quad * 8);
                    f32x4 acc = {0.f, 0.f, 0.f, 0.f};
                    acc = __builtin_amdgcn_mfma_f32_16x16x32_bf16(a0, b0, acc, 0, 0, 0);
                    acc = __builtin_amdgcn_mfma_f32_16x16x32_bf16(a1, b1, acc, 0, 0, 0);
                    const float bv = (mtx == 0) ? bl[c] : (mtx == 1) ? br[c] : 0.f;
                    const int node_base = n0 + m0 + quad * 4;
#pragma unroll
                    for (int r = 0; r < 4; ++r) {
                        const int node = node_base + r;
                        if (node < NN) {
                            const _Float16 hv = (_Float16)(acc[r] + bv);
                            outp[(size_t)node * HID + c] = __builtin_bit_cast(unsigned short, hv);
                        }
                    }
                }
            }
        }
    }
    xsync(grid);

    // ---- P3: attention aggregate (2 nodes/wave, 4 ch/lane) ----------------
    {
        const int ll = lane & 31;
        const int half = lane >> 5;
        const int swzb = (bid & 7) * ((int)gridDim.x >> 3) + (bid >> 3);
        const int wid = __builtin_amdgcn_readfirstlane((swzb * 256 + tid) >> 6);
        const int NP = NN / 2;
        const int qq = NP / nwav;
        const int rr = NP % nwav;
        const int pbeg = wid * qq + (wid < rr ? wid : rr);
        const int pend = pbeg + qq + (wid < rr ? 1 : 0);

        const float4 a4 = *((const float4*)att + ll);
        h2 a01, a23;
        a01.x = (_Float16)(a4.x * 1.44269504f);
        a01.y = (_Float16)(a4.y * 1.44269504f);
        a23.x = (_Float16)(a4.z * 1.44269504f);
        a23.y = (_Float16)(a4.w * 1.44269504f);
        const float4 b4 = *((const float4*)bias + ll);

        for (int p = pbeg; p < pend; ++p) {
            const int n = 2 * p + half;
            const uint2 vr = *((const uint2*)(xrh + (size_t)n * HID) + ll);
            const uint2 vn = *((const uint2*)(xlh + (size_t)n * HID) + ll);
            const uint2 vs = *((const uint2*)(xresh + (size_t)n * HID) + ll);
            int S[8]; uint2 VA[8], VB[8];
#pragma unroll
            for (int u = 0; u < 8; ++u) S[u] = (int)csr[(size_t)n * 64 + u];
            int deg = degv[n];
            deg = min(max(deg, 0), 64);
#pragma unroll
            for (int u = 0; u < 8; ++u) {
                int s = S[u]; if ((unsigned)s >= NN) s = 0;
                VA[u] = *((const uint2*)(xlh + (size_t)s * HID) + ll);
            }

            const h2 xr01 = __builtin_bit_cast(h2, vr.x);
            const h2 xr23 = __builtin_bit_cast(h2, vr.y);
            const h2 xl01 = __builtin_bit_cast(h2, vn.x);
            const h2 xl23 = __builtin_bit_cast(h2, vn.y);
            const h2 t01 = xl01 + xr01;
            const h2 t23 = xl23 + xr23;
            const h2 e01 = __builtin_elementwise_max(t01, t01 * (_Float16)0.2f);
            const h2 e23 = __builtin_elementwise_max(t23, t23 * (_Float16)0.2f);
            const float qs = dpp4_sum(FDOT2A(e23, a23, FDOT2A(e01, a01, 0.f)));
            float den = EXP2(qs);
            const v2f f01 = __builtin_convertvector(xl01, v2f);
            const v2f f23 = __builtin_convertvector(xl23, v2f);
            float c0 = den * f01.x, c1 = den * f01.y, c2 = den * f23.x, c3 = den * f23.y;

            const int degA = __builtin_amdgcn_readlane(deg, 0);
            const int degB = __builtin_amdgcn_readlane(deg, 32);
            const int nb = (max(degA, degB) + 7) >> 3;

            int b = 0;
            for (; b + 2 <= nb; b += 2) {
#pragma unroll
                for (int u = 0; u < 8; ++u) S[u] = (int)csr[(size_t)n * 64 + (b + 1) * 8 + u];
#pragma unroll
                for (int u = 0; u < 8; ++u)
                    edge4(VA[u], xr01, xr23, a01, a23, b * 8 + u < deg, den, c0, c1, c2, c3);
#pragma unroll
                for (int u = 0; u < 8; ++u) {
                    int s = S[u]; if ((unsigned)s >= NN) s = 0;
                    VB[u] = *((const uint2*)(xlh + (size_t)s * HID) + ll);
                }
                if (b + 2 < nb) {
#pragma unroll
                    for (int u = 0; u < 8; ++u) S[u] = (int)csr[(size_t)n * 64 + (b + 2) * 8 + u];
                }
#pragma unroll
                for (int u = 0; u < 8; ++u)
                    edge4(VB[u], xr01, xr23, a01, a23, (b + 1) * 8 + u < deg, den, c0, c1, c2, c3);
                if (b + 2 < nb) {
#pragma unroll
                    for (int u = 0; u < 8; ++u) {
                        int s = S[u]; if ((unsigned)s >= NN) s = 0;
                        VA[u] = *((const uint2*)(xlh + (size_t)s * HID) + ll);
                    }
                }
            }
            if (b < nb) {
#pragma unroll
                for (int u = 0; u < 8; ++u)
                    edge4(VA[u], xr01, xr23, a01, a23, b * 8 + u < deg, den, c0, c1, c2, c3);
            }

            const float inv = 1.f / den;
            const v2f s01 = __builtin_convertvector(__builtin_bit_cast(h2, vs.x), v2f);
            const v2f s23 = __builtin_convertvector(__builtin_bit_cast(h2, vs.y), v2f);
            float4 o;
            o.x = c0 * inv + s01.x + b4.x;
            o.y = c1 * inv + s01.y + b4.y;
            o.z = c2 * inv + s23.x + b4.z;
            o.w = c3 * inv + s23.y + b4.w;
            *((float4*)(hfeat + (size_t)n * HID) + ll) = o;
        }
    }
    xsync(grid);

    // ---- P4: per-graph {Wlin+ELU pool} + MLP (blocks < NG) ----------------
    if (bid < NG) {
        const int g = bid;
        for (int i = tid; i < HID * 16; i += 256) sm.t.sWlin[i] = Wlin[i];
        if (tid < 16)  sm.t.sblin[tid] = blin[tid];
        if (tid < 256) sm.t.sW1[tid] = W1[tid];
        for (int i = tid; i < 512; i += 256) sm.t.sW2[i] = W2[i];
        if (tid < 160) sm.t.sW3[tid] = W3[tid];
        if (tid < 16)  sm.t.sb1[tid] = b1[tid];
        if (tid < 32)  sm.t.sb2[tid] = b2[tid];
        if (tid < 5)   sm.t.sb3[tid] = b3[tid];
        __syncthreads();

        int lo = 0, hi = NN;
        while (lo < hi) { int mid = (lo + hi) >> 1; if (batch[mid] < g) lo = mid + 1; else hi = mid; }
        int lo2 = lo, hi2 = NN;
        while (lo2 < hi2) { int mid = (lo2 + hi2) >> 1; if (batch[mid] < g + 1) lo2 = mid + 1; else hi2 = mid; }
        const int nbeg = lo, nend = lo2;

        float sum16[16];
#pragma unroll
        for (int j = 0; j < 16; ++j) sum16[j] = 0.f;

        for (int n = nbeg + tid; n < nend; n += 256) {
            float acc[16];
#pragma unroll
            for (int j = 0; j < 16; ++j) acc[j] = sm.t.sblin[j];
            const float4* hrow = (const float4*)(hfeat + (size_t)n * HID);
#pragma unroll 8
            for (int kc = 0; kc < 32; ++kc) {
                const float4 v = hrow[kc];
#pragma unroll
                for (int j = 0; j < 16; ++j) {
                    acc[j] += v.x * sm.t.sWlin[(kc * 4 + 0) * 16 + j]
                            + v.y * sm.t.sWlin[(kc * 4 + 1) * 16 + j]
                            + v.z * sm.t.sWlin[(kc * 4 + 2) * 16 + j]
                            + v.w * sm.t.sWlin[(kc * 4 + 3) * 16 + j];
                }
            }
#pragma unroll
            for (int j = 0; j < 16; ++j) {
                float o = acc[j];
                o = o > 0.f ? o : __expf(o) - 1.f;
                sum16[j] += o;
            }
        }

#pragma unroll
        for (int j = 0; j < 16; ++j) {
            float v = sum16[j];
            for (int m = 1; m < 64; m <<= 1) v += __shfl_xor(v, m, 64);
            sum16[j] = v;
        }
        if (lane == 0) {
#pragma unroll
            for (int j = 0; j < 16; ++j) sm.t.red[wv][j] = sum16[j];
        }
        __syncthreads();
        if (tid < 16) {
            const float s = sm.t.red[0][tid] + sm.t.red[1][tid]
                          + sm.t.red[2][tid] + sm.t.red[3][tid];
            sm.t.sg[tid] = s / fmaxf((float)(nend - nbeg), 1.f);
        }
        __syncthreads();
        if (tid < 16) {
            float s = sm.t.sb1[tid];
#pragma unroll
            for (int c = 0; c < 16; ++c) s += sm.t.sg[c] * sm.t.sW1[c * 16 + tid];
            sm.t.sv1[tid] = fmaxf(s, 0.f);
        }
        __syncthreads();
        if (tid < 32) {
            float s = sm.t.sb2[tid];
#pragma unroll
            for (int c = 0; c < 16; ++c) s += sm.t.sv1[c] * sm.t.sW2[c * 32 + tid];
            sm.t.sv2[tid] = fmaxf(s, 0.f);
        }
        __syncthreads();
        if (tid < 5) {
            float s = sm.t.sb3[tid];
#pragma unroll
            for (int c = 0; c < 32; ++c) s += sm.t.sv2[c] * sm.t.sW3[c * 5 + tid];
            out[g * 5 + tid] = s;
        }
    }
}

// ========================= R28 fallback kernels =============================
__global__ __launch_bounds__(256) void k_scatprep(
    const int* __restrict__ ei,
    const float* __restrict__ Wl, const float* __restrict__ Wr,
    const float* __restrict__ Wres, unsigned short* __restrict__ Wt,
    int* __restrict__ cnt, unsigned short* __restrict__ col_src,
    unsigned short* __restrict__ ov)
{
    if (blockIdx.x >= SB) {
        const int i = (blockIdx.x - SB) * 256 + threadIdx.x;
        if (i >= 3 * 64 * HID) return;
        const int m = i >> 13, r = i & 8191, k = r >> 7, c = r & 127;
        const float* W = (m == 0) ? Wl : (m == 1) ? Wr : Wres;
        Wt[(size_t)m * 8192 + c * 64 + k] = (unsigned short)bf16rn(W[k * HID + c]);
        return;
    }
    const int e = blockIdx.x * 256 + threadIdx.x;
    if (e >= NE) return;
    const int s = ei[e];
    const int d = ei[NE + e];
    if ((unsigned)d >= NN) return;
    int xcc;
    asm volatile("s_getreg_b32 %0, hwreg(HW_REG_XCC_ID)" : "=s"(xcc));
    const int g = xcc & (NGRP - 1);
    const int pos = __hip_atomic_fetch_add(&cnt[(size_t)g * NN + d], 1,
                                           __ATOMIC_RELAXED,
                                           __HIP_MEMORY_SCOPE_WORKGROUP);
    if (pos < SLOTG) {
        col_src[((size_t)g * NN + d) * SLOTG + pos] = (unsigned short)s;
    } else {
        const int po = atomicAdd(&cnt[(size_t)NGRP * NN + d], 1);
        if (po < OVS) ov[(size_t)d * OVS + po] = (unsigned short)s;
    }
}

__global__ __launch_bounds__(256) void k_compact(
    const int* __restrict__ cnt, const unsigned short* __restrict__ col_src,
    const unsigned short* __restrict__ ov,
    unsigned short* __restrict__ csr, int* __restrict__ degv)
{
    const int n = blockIdx.x * 4 + (threadIdx.x >> 6);
    if (n >= NN) return;
    const int lane = threadIdx.x & 63;
    const int grp = lane >> 3;
    const int gsl = lane & 7;
    int cg = cnt[(size_t)grp * NN + n];
    cg = min(max(cg, 0), SLOTG);
    int cov = cnt[(size_t)NGRP * NN + n];
    cov = min(max(cov, 0), OVS);
    const bool valid = gsl < cg;
    int slot = 0;
    if (valid) slot = (int)col_src[((size_t)grp * NN + n) * SLOTG + gsl];
    const unsigned long long mv = __ballot(valid);
    const int cn = __popcll(mv);
    const int pv = __popcll(mv & ((1ull << lane) - 1ull));
    const int dst = valid ? pv : (cn + (lane - pv));
    const int rec = __builtin_amdgcn_ds_permute(dst << 2, slot);
    if (lane < cn) csr[(size_t)n * 64 + lane] = (unsigned short)rec;
    const int take = min(cov, 64 - cn);
    if (lane < take) csr[(size_t)n * 64 + cn + lane] = ov[(size_t)n * OVS + lane];
    if (lane == 0) degv[n] = cn + take;
}

__global__ __launch_bounds__(256) void k_work(
    const float* __restrict__ x, const unsigned short* __restrict__ Wt,
    const float* __restrict__ bl, const float* __restrict__ br,
    unsigned short* __restrict__ xlh, unsigned short* __restrict__ xrh,
    unsigned short* __restrict__ xresh)
{
    const int tid = threadIdx.x;
    __shared__ short xb[64 * XP];
    __shared__ short wt[128 * WP];
    const int n0 = blockIdx.x * 64;

#pragma unroll
    for (int i = 0; i < 4; ++i) {
        const int idx = i * 256 + tid;
        const int r = idx >> 4, j4 = idx & 15;
        float4 v = make_float4(0.f, 0.f, 0.f, 0.f);
        if (n0 + r < NN) v = *(const float4*)(x + (size_t)(n0 + r) * IN_CH + j4 * 4);
        uint2 pk;
        pk.x = bf16rn(v.x) | (bf16rn(v.y) << 16);
        pk.y = bf16rn(v.z) | (bf16rn(v.w) << 16);
        *(uint2*)(xb + r * XP + j4 * 4) = pk;
    }

    const int wv = tid >> 6;
    const int lane = tid & 63;
    const int quad = lane >> 4;
    const int mr = lane & 15;
    const int m0 = wv * 16;

    for (int mtx = 0; mtx < 3; ++mtx) {
        const unsigned short* __restrict__ Wtm = Wt + (size_t)mtx * 8192;
        unsigned short* __restrict__ outp = (mtx == 0) ? xlh : (mtx == 1) ? xrh : xresh;

        __syncthreads();
#pragma unroll
        for (int i = 0; i < 4; ++i) {
            const int idx = i * 256 + tid;
            const int c = idx >> 3, k0 = (idx & 7) * 8;
            *(uint4*)(wt + c * WP + k0) = *(const uint4*)(Wtm + c * 64 + k0);
        }
        __syncthreads();

        const frag8 a0 = *(const frag8*)(xb + (m0 + mr) * XP + quad * 8);
        const frag8 a1 = *(const frag8*)(xb + (m0 + mr) * XP + 32 + quad * 8);

#pragma unroll
        for (int nt = 0; nt < 8; ++nt) {
            const int c = nt * 16 + mr;
            const frag8 b0 = *(const frag8*)(wt + c * WP + quad * 8);
            const frag8 b1 = *(const frag8*)(wt + c * WP + 32 + quad * 8);
            f32x4 acc = {0.f, 0.f, 0.f, 0.f};
            acc = __builtin_amdgcn_mfma_f32_16x16x32_bf16(a0, b0, acc, 0, 0, 0);
            acc = __builtin_amdgcn_mfma_f32_16x16x32_bf16(a1, b1, acc, 0, 0, 0);
            const float bv = (mtx == 0) ? bl[c] : (mtx == 1) ? br[c] : 0.f;
            const int node_base = n0 + m0 + quad * 4;
#pragma unroll
            for (int r = 0; r < 4; ++r) {
                const int node = node_base + r;
                if (node < NN) {
                    const _Float16 hv = (_Float16)(acc[r] + bv);
                    outp[(size_t)node * HID + c] = __builtin_bit_cast(unsigned short, hv);
                }
            }
        }
    }
}

__global__ __launch_bounds__(256) void k_agg(
    const unsigned short* __restrict__ xlh, const unsigned short* __restrict__ xrh,
    const unsigned short* __restrict__ xresh,
    const int* __restrict__ degv, const unsigned short* __restrict__ csr,
    const float* __restrict__ att, const float* __restrict__ bias,
    float* __restrict__ hfeat)
{
    const int lane = threadIdx.x & 63;
    const int ll = lane & 31;
    const int half = lane >> 5;
    const int bid = blockIdx.x;
    const int swzb = (bid & 7) * (AGB / 8) + (bid >> 3);
    const int wid = __builtin_amdgcn_readfirstlane((swzb * 256 + (int)threadIdx.x) >> 6);
    const int nwav = (AGB * 256) >> 6;
    const int NP = NN / 2;
    const int qq = NP / nwav;
    const int rr = NP % nwav;
    const int pbeg = wid * qq + (wid < rr ? wid : rr);
    const int pend = pbeg + qq + (wid < rr ? 1 : 0);

    const float4 a4 = *((const float4*)att + ll);
    h2 a01, a23;
    a01.x = (_Float16)(a4.x * 1.44269504f);
    a01.y = (_Float16)(a4.y * 1.44269504f);
    a23.x = (_Float16)(a4.z * 1.44269504f);
    a23.y = (_Float16)(a4.w * 1.44269504f);
    const float4 b4 = *((const float4*)bias + ll);

    for (int p = pbeg; p < pend; ++p) {
        const int n = 2 * p + half;
        const uint2 vr = *((const uint2*)(xrh + (size_t)n * HID) + ll);
        const uint2 vn = *((const uint2*)(xlh + (size_t)n * HID) + ll);
        const uint2 vs = *((const uint2*)(xresh + (size_t)n * HID) + ll);
        int S[8]; uint2 VA[8], VB[8];
#pragma unroll
        for (int u = 0; u < 8; ++u) S[u] = (int)csr[(size_t)n * 64 + u];
        int deg = degv[n];
        deg = min(max(deg, 0), 64);
#pragma unroll
        for (int u = 0; u < 8; ++u) {
            int s = S[u]; if ((unsigned)s >= NN) s = 0;
            VA[u] = *((const uint2*)(xlh + (size_t)s * HID) + ll);
        }

        const h2 xr01 = __builtin_bit_cast(h2, vr.x);
        const h2 xr23 = __builtin_bit_cast(h2, vr.y);
        const h2 xl01 = __builtin_bit_cast(h2, vn.x);
        const h2 xl23 = __builtin_bit_cast(h2, vn.y);
        const h2 t01 = xl01 + xr01;
        const h2 t23 = xl23 + xr23;
        const h2 e01 = __builtin_elementwise_max(t01, t01 * (_Float16)0.2f);
        const h2 e23 = __builtin_elementwise_max(t23, t23 * (_Float16)0.2f);
        const float qs = dpp4_sum(FDOT2A(e23, a23, FDOT2A(e01, a01, 0.f)));
        float den = EXP2(qs);
        const v2f f01 = __builtin_convertvector(xl01, v2f);
        const v2f f23 = __builtin_convertvector(xl23, v2f);
        float c0 = den * f01.x, c1 = den * f01.y, c2 = den * f23.x, c3 = den * f23.y;

        const int degA = __builtin_amdgcn_readlane(deg, 0);
        const int degB = __builtin_amdgcn_readlane(deg, 32);
        const int nb = (max(degA, degB) + 7) >> 3;

        int b = 0;
        for (; b + 2 <= nb; b += 2) {
#pragma unroll
            for (int u = 0; u < 8; ++u) S[u] = (int)csr[(size_t)n * 64 + (b + 1) * 8 + u];
#pragma unroll
            for (int u = 0; u < 8; ++u)
                edge4(VA[u], xr01, xr23, a01, a23, b * 8 + u < deg, den, c0, c1, c2, c3);
#pragma unroll
            for (int u = 0; u < 8; ++u) {
                int s = S[u]; if ((unsigned)s >= NN) s = 0;
                VB[u] = *((const uint2*)(xlh + (size_t)s * HID) + ll);
            }
            if (b + 2 < nb) {
#pragma unroll
                for (int u = 0; u < 8; ++u) S[u] = (int)csr[(size_t)n * 64 + (b + 2) * 8 + u];
            }
#pragma unroll
            for (int u = 0; u < 8; ++u)
                edge4(VB[u], xr01, xr23, a01, a23, (b + 1) * 8 + u < deg, den, c0, c1, c2, c3);
            if (b + 2 < nb) {
#pragma unroll
                for (int u = 0; u < 8; ++u) {
                    int s = S[u]; if ((unsigned)s >= NN) s = 0;
                    VA[u] = *((const uint2*)(xlh + (size_t)s * HID) + ll);
                }
            }
        }
        if (b < nb) {
#pragma unroll
            for (int u = 0; u < 8; ++u)
                edge4(VA[u], xr01, xr23, a01, a23, b * 8 + u < deg, den, c0, c1, c2, c3);
        }

        const float inv = 1.f / den;
        const v2f s01 = __builtin_convertvector(__builtin_bit_cast(h2, vs.x), v2f);
        const v2f s23 = __builtin_convertvector(__builtin_bit_cast(h2, vs.y), v2f);
        float4 o;
        o.x = c0 * inv + s01.x + b4.x;
        o.y = c1 * inv + s01.y + b4.y;
        o.z = c2 * inv + s23.x + b4.z;
        o.w = c3 * inv + s23.y + b4.w;
        *((float4*)(hfeat + (size_t)n * HID) + ll) = o;
    }
}

__global__ __launch_bounds__(256) void k_tail(
    const float* __restrict__ hfeat, const int* __restrict__ batch,
    const float* __restrict__ Wlin, const float* __restrict__ blin,
    const float* __restrict__ W1, const float* __restrict__ b1,
    const float* __restrict__ W2, const float* __restrict__ b2,
    const float* __restrict__ W3, const float* __restrict__ b3,
    float* __restrict__ out)
{
    __shared__ float sWlin[HID * 16];
    __shared__ float sblin[16];
    __shared__ float sW1[256], sb1[16], sW2[512], sb2[32], sW3[160], sb3[5];
    __shared__ float red[256][17];
    __shared__ float sg[16], sv1[16], sv2[32];
    const int g = blockIdx.x;
    const int tid = threadIdx.x;

    for (int i = tid; i < HID * 16; i += 256) sWlin[i] = Wlin[i];
    if (tid < 16)  sblin[tid] = blin[tid];
    if (tid < 256) sW1[tid] = W1[tid];
    for (int i = tid; i < 512; i += 256) sW2[i] = W2[i];
    if (tid < 160) sW3[tid] = W3[tid];
    if (tid < 16)  sb1[tid] = b1[tid];
    if (tid < 32)  sb2[tid] = b2[tid];
    if (tid < 5)   sb3[tid] = b3[tid];
    __syncthreads();

    int lo = 0, hi = NN;
    while (lo < hi) { int mid = (lo + hi) >> 1; if (batch[mid] < g) lo = mid + 1; else hi = mid; }
    int lo2 = lo, hi2 = NN;
    while (lo2 < hi2) { int mid = (lo2 + hi2) >> 1; if (batch[mid] < g + 1) lo2 = mid + 1; else hi2 = mid; }
    const int nbeg = lo, nend = lo2;

    float sum16[16];
#pragma unroll
    for (int j = 0; j < 16; ++j) sum16[j] = 0.f;

    for (int n = nbeg + tid; n < nend; n += 256) {
        float acc[16];
#pragma unroll
        for (int j = 0; j < 16; ++j) acc[j] = sblin[j];
        const float4* hrow = (const float4*)(hfeat + (size_t)n * HID);
#pragma unroll 8
        for (int kc = 0; kc < 32; ++kc) {
            const float4 v = hrow[kc];
#pragma unroll
            for (int j = 0; j < 16; ++j) {
                acc[j] += v.x * sWlin[(kc * 4 + 0) * 16 + j] + v.y * sWlin[(kc * 4 + 1) * 16 + j]
                        + v.z * sWlin[(kc * 4 + 2) * 16 + j] + v.w * sWlin[(kc * 4 + 3) * 16 + j];
            }
        }
#pragma unroll
        for (int j = 0; j < 16; ++j) {
            float o = acc[j];
            o = o > 0.f ? o : __expf(o) - 1.f;
            sum16[j] += o;
        }
    }

#pragma unroll
    for (int j = 0; j < 16; ++j) red[tid][j] = sum16[j];
    __syncthreads();
    for (int s = 128; s > 0; s >>= 1) {
        if (tid < s) {
#pragma unroll
            for (int j = 0; j < 16; ++j) red[tid][j] += red[tid + s][j];
        }
        __syncthreads();
    }

    if (tid < 16) sg[tid] = red[0][tid] / fmaxf((float)(nend - nbeg), 1.f);
    __syncthreads();
    if (tid < 16) {
        float s = sb1[tid];
#pragma unroll
        for (int c = 0; c < 16; ++c) s += sg[c] * sW1[c * 16 + tid];
        sv1[tid] = fmaxf(s, 0.f);
    }
    __syncthreads();
    if (tid < 32) {
        float s = sb2[tid];
#pragma unroll
        for (int c = 0; c < 16; ++c) s += sv1[c] * sW2[c * 32 + tid];
        sv2[tid] = fmaxf(s, 0.f);
    }
    __syncthreads();
    if (tid < 5) {
        float s = sb3[tid];
#pragma unroll
        for (int c = 0; c < 32; ++c) s += sv2[c] * sW3[c * 5 + tid];
        out[g * 5 + tid] = s;
    }
}

extern "C" void kernel_launch(void* const* d_in, const int* in_sizes, int n_in,
                              void* d_out, int out_size, void* d_ws, size_t ws_size,
                              hipStream_t stream)
{
    const float* x    = (const float*)d_in[0];
    const int*   ei   = (const int*)d_in[1];
    const int*   batch= (const int*)d_in[2];
    const float* Wl   = (const float*)d_in[3];
    const float* bl   = (const float*)d_in[4];
    const float* Wr   = (const float*)d_in[5];
    const float* br   = (const float*)d_in[6];
    const float* att  = (const float*)d_in[7];
    const float* Wres = (const float*)d_in[8];
    const float* bias = (const float*)d_in[9];
    const float* Wlin = (const float*)d_in[10];
    const float* blin = (const float*)d_in[11];
    const float* W1   = (const float*)d_in[12];
    const float* b1   = (const float*)d_in[13];
    const float* W2   = (const float*)d_in[14];
    const float* b2   = (const float*)d_in[15];
    const float* W3   = (const float*)d_in[16];
    const float* b3   = (const float*)d_in[17];
    float* out = (float*)d_out;

    uintptr_t p = (uintptr_t)d_ws;
    unsigned short* xlh   = (unsigned short*)p; p += (size_t)NN * HID * 2;
    unsigned short* xrh   = (unsigned short*)p; p += (size_t)NN * HID * 2;
    unsigned short* xresh = (unsigned short*)p; p += (size_t)NN * HID * 2;
    p = (p + 15) & ~(uintptr_t)15;
    float* hfeat  = (float*)p; p += (size_t)NN * HID * 4;
    int* cnt      = (int*)p;   p += (size_t)(NGRP + 1) * NN * 4;
    unsigned short* col_src = (unsigned short*)p; p += (size_t)NGRP * NN * SLOTG * 2;
    unsigned short* ovp     = (unsigned short*)p; p += (size_t)NN * OVS * 2;
    p = (p + 15) & ~(uintptr_t)15;
    unsigned short* csr     = (unsigned short*)p; p += (size_t)NN * 64 * 2;
    int* degv               = (int*)p;            p += (size_t)NN * 4;
    p = (p + 15) & ~(uintptr_t)15;
    unsigned short* Wt      = (unsigned short*)p; p += (size_t)3 * 64 * HID * 2;

    // ---- occupancy-derived cooperative grid (cached; -1 = mega unusable) --
    static int mega_grid = 0;
    if (mega_grid == 0) {
        int perCU = 0;
        hipError_t e1 = hipOccupancyMaxActiveBlocksPerMultiprocessor(&perCU, k_mega, 256, 0);
        int cus = 0;
        hipDeviceProp_t prop;
        hipError_t e2 = hipGetDeviceProperties(&prop, 0);
        if (e2 == hipSuccess) cus = prop.multiProcessorCount;
        if (e1 == hipSuccess && perCU > 0 && cus > 0) {
            long g = (long)perCU * (long)cus;
            g -= g % 8;                       // swizzle bijectivity
            if (g > 2048) g = 2048;
            mega_grid = (g >= 1024) ? (int)g : -1;   // need >= GB2 (782) + margin
        } else {
            mega_grid = -1;
        }
        (void)hipGetLastError();              // clear any sticky error
    }

    bool ran_mega = false;
    if (mega_grid > 0) {
        void* args[] = {
            (void*)&x, (void*)&ei, (void*)&Wl, (void*)&bl, (void*)&Wr, (void*)&br,
            (void*)&Wres, (void*)&att, (void*)&bias, (void*)&Wlin, (void*)&blin,
            (void*)&W1, (void*)&b1, (void*)&W2, (void*)&b2, (void*)&W3, (void*)&b3,
            (void*)&batch, (void*)&out,
            (void*)&xlh, (void*)&xrh, (void*)&xresh, (void*)&hfeat,
            (void*)&cnt, (void*)&col_src, (void*)&ovp, (void*)&csr, (void*)&degv,
            (void*)&Wt
        };
        hipError_t e = hipLaunchCooperativeKernel((void*)k_mega, dim3(mega_grid),
                                                  dim3(256), args, 0, stream);
        if (e == hipSuccess) {
            ran_mega = true;
        } else {
            (void)hipGetLastError();          // clear; remember mega is unusable
            mega_grid = -1;
        }
    }

    if (!ran_mega) {                          // R28 multi-kernel path (passing, 217us)
        hipMemsetAsync(cnt, 0, (size_t)(NGRP + 1) * NN * sizeof(int), stream);
        k_scatprep<<<SB + PB, 256, 0, stream>>>(ei, Wl, Wr, Wres, Wt, cnt, col_src, ovp);
        k_compact<<<(NN + 3) / 4, 256, 0, stream>>>(cnt, col_src, ovp, csr, degv);
        k_work<<<GB2, 256, 0, stream>>>(x, Wt, bl, br, xlh, xrh, xresh);
        k_agg<<<AGB, 256, 0, stream>>>(xlh, xrh, xresh, degv, csr, att, bias, hfeat);
        k_tail<<<NG, 256, 0, stream>>>(hfeat, batch, Wlin, blin,
                                       W1, b1, W2, b2, W3, b3, out);
    }
}